// Round 5
// baseline (270.023 us; speedup 1.0000x reference)
//
#include <hip/hip_runtime.h>
#include <stdint.h>

#define GD    34
#define GP    36          // padded grid (zero halo)
#define NPIX  1156
#define NT    512
#define NW    8           // waves per block
#define NB    1024
#define TPR   12          // 3-pixel strips per row (12*3=36 >= 34)
#define TUSED 408         // 34 rows * 12 strips
#define SP    3           // strip length

// wave0 scans the 1024-bin LDS histogram, finds the bin containing rank KK,
// writes sel_bin/sel_rem, zeroes the histogram behind itself.
#define SCAN_PASS(KK) do {                                                         \
    if (wid == 0) {                                                                \
      const int base2 = lane << 4;                                                 \
      int c16[16]; int csum = 0;                                                   \
      _Pragma("unroll")                                                            \
      for (int j = 0; j < 16; ++j) { c16[j] = hist[base2+j]; hist[base2+j] = 0; csum += c16[j]; } \
      int inc = csum;                                                              \
      _Pragma("unroll")                                                            \
      for (int off2 = 1; off2 < 64; off2 <<= 1) { int vv = __shfl_up(inc, off2); if (lane >= off2) inc += vv; } \
      const int excl = inc - csum;                                                 \
      if ((KK) >= excl && (KK) < inc) {                                            \
        int rem = (KK) - excl; int cum = 0;                                        \
        _Pragma("unroll")                                                          \
        for (int j = 0; j < 16; ++j) {                                             \
          if (rem >= cum && rem < cum + c16[j]) { sel_bin = base2 + j; sel_rem = rem - cum; } \
          cum += c16[j];                                                           \
        }                                                                          \
      }                                                                            \
    }                                                                              \
  } while (0)

#define SCRN 3608   // x0buf[1296] | x1s[1156] | x2s[1156]; hist aliases x1s

// Prep: pack per-o weights contiguously -> 2 wide s_loads per o-iteration.
// [o][20]: w0..w11, b1, q0, q1, q2, q3, pad*3
__global__ void pack_w(const float* __restrict__ fc1_w, const float* __restrict__ fc1_b,
                       const float* __restrict__ fc2_w, float* __restrict__ wp) {
  int o = threadIdx.x;
  if (o < 64) {
#pragma unroll
    for (int j = 0; j < 12; ++j) wp[o*20+j] = fc1_w[o*12+j];
    wp[o*20+12] = fc1_b[o];
    wp[o*20+13] = fc2_w[o];
    wp[o*20+14] = fc2_w[64+o];
    wp[o*20+15] = fc2_w[128+o];
    wp[o*20+16] = fc2_w[192+o];
  }
}

__global__ __launch_bounds__(NT) __attribute__((amdgpu_waves_per_eu(8, 8)))
void ca_kernel(const float* __restrict__ cell_in,   // [B,4,34,34]
               const float* __restrict__ food_in,   // [B,34,34]
               const float* __restrict__ fc2_b,     // [4]
               const float* __restrict__ sk_g,      // [19,19]
               const int*   __restrict__ steps_p,
               const float* __restrict__ wp,        // packed weights [64][20]
               float* __restrict__ out)             // [cell | food | tpv | lc]
{
  __shared__ float cbuf[3][GP*GP];   // ch0..2; ch3 == scent (step-invariant), never stored
  __shared__ float scratch[SCRN];
  __shared__ int   icl[2][NW];
  __shared__ int   inzaz[NW];
  __shared__ int   sel_bin, sel_rem;
  __shared__ float fsum[NW];
  __shared__ int   lcnt[NW];

  float* x0buf = scratch;                       // 36x36 halo'd, x_new ch0 (pre-mask/clip)
  float* x1s   = scratch + 1296;                // flat [1156] staging of x_new ch1
  float* x2s   = scratch + 2452;                // flat [1156] staging of x_new ch2
  int*   hist  = (int*)(scratch + 1296);        // aliases x1s: only live inside radix path

  const int tid  = threadIdx.x;
  const int b    = blockIdx.x;
  const int lane = tid & 63;
  const int wid  = tid >> 6;
  const int nsteps = steps_p[0];

  const bool tval = (tid < TUSED);
  const int  trow = tval ? (tid / TPR) : 0;
  const int  c0   = tval ? ((tid % TPR) * SP) : 0;
  const int  nval = tval ? ((c0 <= 31) ? 3 : 1) : 0;    // last strip covers col 33 only
  const int  pb0  = tval ? ((trow+1)*GP + c0 + 1) : 37; // padded base (safe interior if idle)
  const int  p0   = trow*GD + c0;                       // flat pixel base

  // loop-invariant window bases (rows +-2 clamped into the zero halo)
  const int r0b = pb0 - (c0 + 1);               // prow*GP
  const int rm1 = r0b - GP, rp1 = r0b + GP;     // prow in [1,34] -> always in bounds
  const int rm2 = (r0b - 2*GP < 0) ? 0 : (r0b - 2*GP);
  const int rp2 = (r0b + 2*GP > 35*GP) ? 35*GP : (r0b + 2*GP);

  // ---------------- init ----------------
  for (int idx = tid; idx < 3*GP*GP; idx += NT) (&cbuf[0][0])[idx] = 0.f;
  for (int idx = tid; idx < SCRN;    idx += NT) scratch[idx] = 0.f;
  __syncthreads();

  float v3k[SP];
  int cnt0 = 0;
#pragma unroll
  for (int j = 0; j < SP; ++j) {
    v3k[j] = 0.f;
    if (j < nval) {
      int p = p0 + j;
      const float* gi = cell_in + (size_t)b*4*NPIX + p;
      float v0 = gi[0], v1 = gi[NPIX], v2 = gi[2*NPIX], v3 = gi[3*NPIX];
      cbuf[0][pb0+j] = v0; cbuf[1][pb0+j] = v1; cbuf[2][pb0+j] = v2;
      v3k[j] = v3;
      cnt0 += (v0 > 0.8f) ? 1 : 0;
      scratch[(trow+9)*52 + (c0+j+9)] = food_in[(size_t)b*NPIX + p];  // 9-halo 52x52
    }
  }
#pragma unroll
  for (int off = 32; off; off >>= 1) cnt0 += __shfl_down(cnt0, off);
  if (lane == 0) icl[0][wid] = cnt0;
  __syncthreads();

  // scent: 19x19 gaussian conv, once
  float scent[SP];
#pragma unroll
  for (int j = 0; j < SP; ++j) {
    float ssum = 0.f;
    if (j < nval) {
      for (int dr = 0; dr < 19; ++dr) {
        const float* frow = scratch + (trow+dr)*52 + (c0+j);
        const float* krow = sk_g + dr*19;
#pragma unroll
        for (int dc = 0; dc < 19; ++dc) ssum = fmaf(frow[dc], krow[dc], ssum);
      }
    }
    scent[j] = ssum;
  }
  __syncthreads();
  for (int idx = tid; idx < SCRN; idx += NT) scratch[idx] = 0.f;
  __syncthreads();
#pragma unroll
  for (int j = 0; j < SP; ++j) if (j < nval) x0buf[pb0+j] = scent[j];
  __syncthreads();
  // ch3 := scent every step -> its sobels are step-invariant
  float sxs[SP], sys[SP];
#pragma unroll
  for (int j = 0; j < SP; ++j) {
    const int bb = (j < nval) ? (pb0 + j) : pb0;
    float t00=x0buf[bb-GP-1], t01=x0buf[bb-GP], t02=x0buf[bb-GP+1];
    float t10=x0buf[bb-1],                      t12=x0buf[bb+1];
    float t20=x0buf[bb+GP-1], t21=x0buf[bb+GP], t22=x0buf[bb+GP+1];
    sxs[j] = ((t02 - t00) + 2.f*(t12 - t10) + (t22 - t20)) * 0.125f;
    sys[j] = ((t20 - t00) + 2.f*(t21 - t01) + (t22 - t02)) * 0.125f;
  }
  // x0buf content is stale-safe (only consumed at pixels whose window was refreshed)

  const float b2r0 = fc2_b[0], b2r1 = fc2_b[1], b2r2 = fc2_b[2], b2r3 = fc2_b[3];

  // ---------------- steps ----------------
  for (int s = 0; s < nsteps; ++s) {
    __syncthreads();                       // syncW: prev writeback -> window reads
    // --- B: fused premask (maxpool3>0.1) + activity (maxpool5>0.1) ---
    // dilate3(maxpool3(z)>0.1) == maxpool5(z)>0.1; zero-halo clamps are exact.
    float cm3[7], cm5[7];
#pragma unroll
    for (int jc = 0; jc < 7; ++jc) {
      cm3[jc] = 0.f; cm5[jc] = 0.f;
      if (jc < nval + 4) {
        int pc = c0 - 1 + jc;                       // padded col index c0p-2+jc
        pc = (pc < 0) ? 0 : ((pc > 35) ? 35 : pc);  // clamp into zero halo (exact)
        const float* cb = cbuf[0];
        float c3 = fmaxf(fmaxf(cb[rm1+pc], cb[r0b+pc]), cb[rp1+pc]);
        cm3[jc] = c3;
        cm5[jc] = fmaxf(fmaxf(cb[rm2+pc], cb[rp2+pc]), c3);
      }
    }
    unsigned pm = 0;
#pragma unroll
    for (int j = 0; j < SP; ++j)
      if (j < nval && fmaxf(fmaxf(cm3[j+1], cm3[j+2]), cm3[j+3]) > 0.1f) pm |= (1u << j);
    // --- per-pixel gated MLP ---
#pragma unroll
    for (int j = 0; j < SP; ++j) {
      float a5 = fmaxf(fmaxf(fmaxf(cm5[j], cm5[j+1]), fmaxf(cm5[j+2], cm5[j+3])), cm5[j+4]);
      int acti = (j < nval) && (a5 > 0.1f);
      if (__any(acti)) {
        const int bb = (j < nval) ? (pb0 + j) : pb0;
        float y0,y1,y2,y4,y5,y6,y8,y9,y10;
        {
          const float* cb = cbuf[0];
          float t00=cb[bb-GP-1], t01=cb[bb-GP], t02=cb[bb-GP+1];
          float t10=cb[bb-1],    t11=cb[bb],    t12=cb[bb+1];
          float t20=cb[bb+GP-1], t21=cb[bb+GP], t22=cb[bb+GP+1];
          y0 = t11;
          y4 = ((t02 - t00) + 2.f*(t12 - t10) + (t22 - t20)) * 0.125f;
          y8 = ((t20 - t00) + 2.f*(t21 - t01) + (t22 - t02)) * 0.125f;
        }
        {
          const float* cb = cbuf[1];
          float t00=cb[bb-GP-1], t01=cb[bb-GP], t02=cb[bb-GP+1];
          float t10=cb[bb-1],    t11=cb[bb],    t12=cb[bb+1];
          float t20=cb[bb+GP-1], t21=cb[bb+GP], t22=cb[bb+GP+1];
          y1 = t11;
          y5 = ((t02 - t00) + 2.f*(t12 - t10) + (t22 - t20)) * 0.125f;
          y9 = ((t20 - t00) + 2.f*(t21 - t01) + (t22 - t02)) * 0.125f;
        }
        {
          const float* cb = cbuf[2];
          float t00=cb[bb-GP-1], t01=cb[bb-GP], t02=cb[bb-GP+1];
          float t10=cb[bb-1],    t11=cb[bb],    t12=cb[bb+1];
          float t20=cb[bb+GP-1], t21=cb[bb+GP], t22=cb[bb+GP+1];
          y2 = t11;
          y6 = ((t02 - t00) + 2.f*(t12 - t10) + (t22 - t20)) * 0.125f;
          y10= ((t20 - t00) + 2.f*(t21 - t01) + (t22 - t02)) * 0.125f;
        }
        const float y3 = scent[j], y7 = sxs[j], y11 = sys[j];
        float u0 = b2r0, u1 = b2r1, u2 = b2r2, u3 = b2r3;
        for (int o = 0; o < 64; ++o) {     // packed wave-uniform scalar loads
          const float* wr = wp + o*20;
          float t = wr[12];
          t = fmaf(y0, wr[0], t);  t = fmaf(y1, wr[1], t);
          t = fmaf(y2, wr[2], t);  t = fmaf(y3, wr[3], t);
          t = fmaf(y4, wr[4], t);  t = fmaf(y5, wr[5], t);
          t = fmaf(y6, wr[6], t);  t = fmaf(y7, wr[7], t);
          t = fmaf(y8, wr[8], t);  t = fmaf(y9, wr[9], t);
          t = fmaf(y10, wr[10], t); t = fmaf(y11, wr[11], t);
          t = fmaxf(t, 0.f);
          u0 = fmaf(t, wr[13], u0);
          u1 = fmaf(t, wr[14], u1);
          u2 = fmaf(t, wr[15], u2);
          u3 = fmaf(t, wr[16], u3);
        }
        v3k[j] = y3 + u3;                  // x_new ch3, pre-clip, held in-place
        if (j < nval) {
          x0buf[bb]   = y0 + u0;           // x_new ch0, pre-mask/clip (for postmask pool)
          x1s[p0 + j] = y1 + u1;
          x2s[p0 + j] = y2 + u2;
        }
      }
    }
    __syncthreads();                       // sync2
    // --- C: postmask (only where premask), masks+clips, counts ---
    unsigned pq = 0;
    float midv[SP];
#pragma unroll
    for (int j = 0; j < SP; ++j) midv[j] = 0.f;
    if (pm) {
      float dm[SP+2];
#pragma unroll
      for (int jc = 0; jc < SP+2; ++jc) {
        dm[jc] = 0.f;
        if (jc < nval + 2) {
          const int a = pb0 - 1 + jc;
          float u = x0buf[a-GP], m = x0buf[a], d = x0buf[a+GP];
          dm[jc] = fmaxf(fmaxf(u, m), d);
          if (jc >= 1 && jc <= nval) midv[jc-1] = m;   // own x_new ch0 values
        }
      }
#pragma unroll
      for (int j = 0; j < SP; ++j)
        if (fmaxf(fmaxf(dm[j], dm[j+1]), dm[j+2]) > 0.1f) pq |= (1u << j);
    }
    int packed = 0;                        // nz | az<<16
    float v0s[SP];
#pragma unroll
    for (int j = 0; j < SP; ++j) {
      v0s[j] = 0.f;
      if (j < nval) {
        bool alive = ((pm >> j) & 1u) && ((pq >> j) & 1u);
        float v0 = 0.f, v1 = 0.f, v2 = 0.f, v3 = 0.f;
        if (alive) {
          v0 = fminf(fmaxf(midv[j],      0.f),  1.f);
          v1 = fminf(fmaxf(x1s[p0+j], -10.f), 10.f);
          v2 = fminf(fmaxf(x2s[p0+j], -10.f), 10.f);
          v3 = fminf(fmaxf(v3k[j],    -10.f), 10.f);
        }
        cbuf[1][pb0+j] = v1; cbuf[2][pb0+j] = v2; v3k[j] = v3;
        v0s[j] = v0;
        int zer = (v0 == 0.f) ? 1 : 0;
        int azf = (zer && v1 == 0.f && v2 == 0.f && v3 == 0.f) ? 1 : 0;
        packed += zer + (azf << 16);
      }
    }
#pragma unroll
    for (int off = 32; off; off >>= 1) packed += __shfl_down(packed, off);
    if (lane == 0) inzaz[wid] = packed;
    __syncthreads();                       // sync3 (x1s/x2s fully consumed after this)
    int t01 = 0, cl = 0;
#pragma unroll
    for (int w = 0; w < NW; ++w) { t01 += inzaz[w]; cl += icl[s&1][w]; }
    const int nz = t01 & 0xffff, az = t01 >> 16;
    const int k  = (cl < NPIX) ? cl : (NPIX-1);
    float kth = 0.f;
    if (k >= nz) {                         // rare: k-th value nonzero -> 3-pass radix select
      hist[tid] = 0; hist[tid+512] = 0;    // hist aliases x1s
      __syncthreads();
      const int k2 = k - nz;
#pragma unroll
      for (int j = 0; j < SP; ++j) {
        unsigned u = __float_as_uint(v0s[j]);
        if (j < nval && u != 0u) atomicAdd(&hist[u >> 20], 1);
      }
      __syncthreads();
      SCAN_PASS(k2);
      __syncthreads();
      const int bin1 = sel_bin; const int kr2 = sel_rem;
#pragma unroll
      for (int j = 0; j < SP; ++j) {
        unsigned u = __float_as_uint(v0s[j]);
        if (j < nval && u != 0u && (u >> 20) == (unsigned)bin1)
          atomicAdd(&hist[(u >> 10) & 1023u], 1);
      }
      __syncthreads();
      SCAN_PASS(kr2);
      __syncthreads();
      const int bin2 = sel_bin; const int kr3 = sel_rem;
      const unsigned pref2 = (((unsigned)bin1) << 10) | (unsigned)bin2;
#pragma unroll
      for (int j = 0; j < SP; ++j) {
        unsigned u = __float_as_uint(v0s[j]);
        if (j < nval && u != 0u && (u >> 10) == pref2)
          atomicAdd(&hist[u & 1023u], 1);
      }
      __syncthreads();
      SCAN_PASS(kr3);
      __syncthreads();
      kth = __uint_as_float((((unsigned)bin1) << 20) | (((unsigned)bin2) << 10) | (unsigned)sel_bin);
      // SCAN_PASS self-clears hist -> x1s region left zeroed
    }
    // --- writeback + next step's living count ---
    int cnt = 0;
#pragma unroll
    for (int j = 0; j < SP; ++j) {
      if (j < nval) {
        float w0 = (v0s[j] > kth) ? v0s[j] : 0.f;
        cbuf[0][pb0+j] = w0;
        cnt += (w0 > 0.8f) ? 1 : 0;
      }
    }
#pragma unroll
    for (int off = 32; off; off >>= 1) cnt += __shfl_down(cnt, off);
    if (lane == 0) icl[(s+1)&1][wid] = cnt;
    if (az == NPIX) break;                 // all-zero state is an exact fixed point
  }

  // ---------------- epilogue ----------------
  const size_t CELL_N = (size_t)4*NPIX*NB;
  const size_t FOOD_N = (size_t)NPIX*NB;
  float tp = 0.f; int lcv = 0;
#pragma unroll
  for (int j = 0; j < SP; ++j) {
    if (j < nval) {
      const int p = p0 + j;
      float c0v = cbuf[0][pb0+j], c1 = cbuf[1][pb0+j], c2 = cbuf[2][pb0+j]; // self-written
      size_t go = (size_t)b*4*NPIX + p;
      out[go]          = c0v;
      out[go +   NPIX] = c1;
      out[go + 2*NPIX] = c2;
      out[go + 3*NPIX] = v3k[j];
      out[CELL_N + (size_t)b*NPIX + p] = food_in[(size_t)b*NPIX + p];
      tp += c0v;
      lcv += (c0v > 0.1f) ? 1 : 0;
    }
  }
#pragma unroll
  for (int off = 32; off; off >>= 1) { tp += __shfl_down(tp, off); lcv += __shfl_down(lcv, off); }
  if (lane == 0) { fsum[wid] = tp; lcnt[wid] = lcv; }
  __syncthreads();
  if (tid == 0) {
    float tps = 0.f; int lcs = 0;
#pragma unroll
    for (int w = 0; w < NW; ++w) { tps += fsum[w]; lcs += lcnt[w]; }
    out[CELL_N + FOOD_N + b]      = tps;
    out[CELL_N + FOOD_N + NB + b] = (float)lcs;
  }
}

extern "C" void kernel_launch(void* const* d_in, const int* in_sizes, int n_in,
                              void* d_out, int out_size, void* d_ws, size_t ws_size,
                              hipStream_t stream) {
  const float* cell  = (const float*)d_in[0];
  const float* food  = (const float*)d_in[1];
  const float* fc1w  = (const float*)d_in[2];
  const float* fc1b  = (const float*)d_in[3];
  const float* fc2w  = (const float*)d_in[4];
  const float* fc2b  = (const float*)d_in[5];
  const float* sk    = (const float*)d_in[6];
  const int*   steps = (const int*)d_in[7];
  float* out = (float*)d_out;
  float* wp  = (float*)d_ws;                       // 64*20*4 = 5120 B of scratch
  pack_w<<<1, 64, 0, stream>>>(fc1w, fc1b, fc2w, wp);
  ca_kernel<<<NB, NT, 0, stream>>>(cell, food, fc2b, sk, steps, wp, out);
}